// Round 16
// baseline (45.971 us; speedup 1.0000x reference)
//
#include <hip/hip_runtime.h>
#include <cmath>

#define THREADS 256
#define NCELL 10
#define DDIM 9

#define LN2F 0.69314718056f
#define RLN2F 1.4426950408889634f  /* 1/ln2 */
#define K10L 14.426950408889634f   /* 10/ln2 */
#define LIN_THR_L 1.442695e-10f    /* 1e-10/ln2 */

typedef float f32x2 __attribute__((ext_vector_type(2)));

__device__ __forceinline__ f32x2 fma2(f32x2 a, f32x2 b, f32x2 c) {
  return __builtin_elementwise_fma(a, b, c);   // v_pk_fma_f32 on gfx950
}
__device__ __forceinline__ f32x2 max2(f32x2 a, f32x2 b) {
  return __builtin_elementwise_max(a, b);      // v_pk_max_f32
}
// Raw HW transcendentals (v_log_f32 IS log2, v_exp_f32 IS exp2; NaN for
// negative log input -> ordered compares false, which we exploit).
__device__ __forceinline__ float log2_hw(float x) {
  float r; asm("v_log_f32 %0, %1" : "=v"(r) : "v"(x)); return r;
}
__device__ __forceinline__ float exp2_hw(float x) {
  float r; asm("v_exp_f32 %0, %1" : "=v"(r) : "v"(x)); return r;
}

struct Basis { float Bt[DDIM][2 * NCELL]; }; // Bt[t][l] = B[l][t]

// Reproduce numpy.linalg.svd(L) Vt[11:] rows: LAPACK dgesdd Path 4t leaves
// rows m..n-1 of VT equal to the LQ-factorization orthogonal complement.
static void compute_basis_host(Basis* bs) {
  double L[11][20];
  for (int r = 0; r < 11; ++r)
    for (int c = 0; c < 20; ++c) L[r][c] = 0.0;
  for (int k = 1; k < NCELL; ++k) {
    double xk = (double)k / (double)NCELL;
    L[k - 1][2 * (k - 1)] = xk;
    L[k - 1][2 * (k - 1) + 1] = 1.0;
    L[k - 1][2 * k] = -xk;
    L[k - 1][2 * k + 1] = -1.0;
  }
  L[NCELL - 1][1] = 1.0;
  L[NCELL][2 * (NCELL - 1)] = 1.0;
  L[NCELL][2 * (NCELL - 1) + 1] = 1.0;

  double v[11][20];
  double tau[11];
  for (int i = 0; i < 11; ++i) {
    double alpha = L[i][i];
    double xn2 = 0.0;
    for (int l = i + 1; l < 20; ++l) xn2 += L[i][l] * L[i][l];
    double xnorm = sqrt(xn2);
    for (int l = 0; l < 20; ++l) v[i][l] = 0.0;
    v[i][i] = 1.0;
    if (xnorm == 0.0) {
      tau[i] = 0.0;
    } else {
      double beta = sqrt(alpha * alpha + xn2);
      if (alpha >= 0.0) beta = -beta;        // dlarfg: beta = -sign(alpha)*norm
      tau[i] = (beta - alpha) / beta;
      double sc = 1.0 / (alpha - beta);
      for (int l = i + 1; l < 20; ++l) v[i][l] = L[i][l] * sc;
      L[i][i] = beta;
      for (int j = i + 1; j < 11; ++j) {
        double w = 0.0;
        for (int l = i; l < 20; ++l) w += L[j][l] * v[i][l];
        w *= tau[i];
        for (int l = i; l < 20; ++l) L[j][l] -= w * v[i][l];
      }
    }
  }
  for (int j = 11; j < 20; ++j) {
    double q[20];
    for (int l = 0; l < 20; ++l) q[l] = 0.0;
    q[j] = 1.0;
    for (int i = 10; i >= 0; --i) {
      double w = 0.0;
      for (int l = i; l < 20; ++l) w += v[i][l] * q[l];
      w *= tau[i];
      for (int l = i; l < 20; ++l) q[l] -= w * v[i][l];
    }
    for (int l = 0; l < 20; ++l) bs->Bt[j - 11][l] = (float)q[l];
  }
}

// Per-MLP folds (130 floats each; m1 at ws[0], m2 at ws[130]):
//  [0:10)    W01[j]  = sum_r w0[r]*w1[r,j]       (layer0+1 fold: NO ReLU between)
//  [10:20)   B01[j]  = sum_r b0[r]*w1[r,j] + b1[j]
//  [20:120)  W3V[r][k] = sum_t w3[r,t]*VB[t][k+1], k=0..8; k=9 -> 0 (v10 pad)
//  [120:130) B3V[k]  = sum_t b3[t]*VB[t][k+1],  k=0..8; k=9 -> 0
__global__ void fold_kernel(
    const float* __restrict__ w0_1, const float* __restrict__ b0_1,
    const float* __restrict__ w1_1, const float* __restrict__ b1_1,
    const float* __restrict__ w3_1, const float* __restrict__ b3_1,
    const float* __restrict__ w0_2, const float* __restrict__ b0_2,
    const float* __restrict__ w1_2, const float* __restrict__ b1_2,
    const float* __restrict__ w3_2, const float* __restrict__ b3_2,
    float* __restrict__ ws, Basis bb) {
  for (int f = threadIdx.x; f < 260; f += THREADS) {
    int m = f / 130;
    int j = f % 130;
    const float* w0 = (m == 0) ? w0_1 : w0_2;
    const float* b0 = (m == 0) ? b0_1 : b0_2;
    const float* w1 = (m == 0) ? w1_1 : w1_2;
    const float* w3 = (m == 0) ? w3_1 : w3_2;
    const float* b3 = (m == 0) ? b3_1 : b3_2;
    const float* b1 = (m == 0) ? b1_1 : b1_2;
    float val = 0.0f;
    if (j < 10) {
      for (int r = 0; r < 10; ++r) val += w0[r] * w1[r * 10 + j];
    } else if (j < 20) {
      int jj = j - 10;
      for (int r = 0; r < 10; ++r) val += b0[r] * w1[r * 10 + jj];
      val += b1[jj];
    } else if (j < 120) {
      int jj = j - 20;
      int r = jj / 10, k = jj % 10;
      if (k < 9) {
        float g = (float)(k + 1) * 0.1f;
        for (int t = 0; t < DDIM; ++t)
          val += w3[r * DDIM + t] * (bb.Bt[t][2 * (k + 1)] * g + bb.Bt[t][2 * (k + 1) + 1]);
      }
    } else {
      int k = j - 120;
      if (k < 9) {
        float g = (float)(k + 1) * 0.1f;
        for (int t = 0; t < DDIM; ++t)
          val += b3[t] * (bb.Bt[t][2 * (k + 1)] * g + bb.Bt[t][2 * (k + 1) + 1]);
      }
    }
    ws[f] = val;
  }
}

// Folded MLP: h1 = relu(x*W01+B01); h2 = relu(h1@w2+b2); v1..v9 = h2@W3V+B3V
// (v0 = v10 = 0). LDS slot per cell: (aL = a/ln2, raL = rcp(aL)) — rcp in the
// ILP-rich section. vL never goes to LDS: the flow's x0 (hence c0) is known
// BEFORE this runs, so entry values v[c0], v[c0+1] are register-selected here.
__device__ __forceinline__ void mlp_A(float xin,
    const float* __restrict__ w2, const float* __restrict__ b2,
    const float* __restrict__ wbf,     // 130 floats
    f32x2* alcol, int c0, float xflow,
    float& aL0, float& raL0, float& v0, float& aminL, float& bmin) {
  const f32x2* W01 = (const f32x2*)wbf;         // [0:5)
  const f32x2* B01 = W01 + 5;                   // [5:10)
  const f32x2* W3V = W01 + 10;                  // [10:60)
  const f32x2* B3V = W01 + 60;                  // [60:65)
  const f32x2* w2p = (const f32x2*)w2;
  const f32x2* b2p = (const f32x2*)b2;

  f32x2 h1[5], h2[5];
  f32x2 xx = {xin, xin};
  f32x2 zero = {0.0f, 0.0f};
#pragma unroll
  for (int p = 0; p < 5; ++p) h1[p] = max2(fma2(xx, W01[p], B01[p]), zero);

#pragma unroll
  for (int p = 0; p < 5; ++p) h2[p] = b2p[p];
#pragma unroll
  for (int r = 0; r < 10; ++r) {
    float h = h1[r >> 1][r & 1];
    f32x2 hh = {h, h};
#pragma unroll
    for (int p = 0; p < 5; ++p) h2[p] = fma2(hh, w2p[r * 5 + p], h2[p]);
  }
#pragma unroll
  for (int p = 0; p < 5; ++p) h2[p] = max2(h2[p], zero);

  f32x2 vp[5];                                   // (v1,v2)..(v9,v10=0)
#pragma unroll
  for (int p = 0; p < 5; ++p) vp[p] = B3V[p];
#pragma unroll
  for (int r = 0; r < 10; ++r) {
    float h = h2[r >> 1][r & 1];
    f32x2 hh = {h, h};
#pragma unroll
    for (int p = 0; p < 5; ++p) vp[p] = fma2(hh, W3V[r * 5 + p], vp[p]);
  }

  float v[NCELL + 1];
  v[0] = 0.0f;
#pragma unroll
  for (int k = 1; k <= NCELL; ++k) v[k] = vp[(k - 1) >> 1][(k - 1) & 1];

  float amn = 1e30f, bmn = 1e30f;
  float vs = v[0], vh = v[1];
#pragma unroll
  for (int c = 0; c < NCELL; ++c) {
    float aL = (v[c + 1] - v[c]) * K10L;
    f32x2 s; s[0] = aL; s[1] = __builtin_amdgcn_rcpf(aL);
    alcol[c * THREADS] = s;
    amn = fminf(amn, fabsf(aL));
    if (c >= 1) {
      bmn = fminf(bmn, fabsf(v[c]));
      bool e = (c0 == c);
      vs = e ? v[c] : vs;
      vh = e ? v[c + 1] : vh;
    }
  }
  aminL = amn;
  bmin = bmn;
  aL0 = (vh - vs) * K10L;              // bit-identical to stored aL[c0]
  raL0 = __builtin_amdgcn_rcpf(aL0);
  v0 = fmaf(aL0, (xflow - (float)c0 * 0.1f) * LN2F, vs);
}

// FAST cell-hop loop. u = |v| in LINEAR space (sign constant along the
// monotone trajectory; u_far = u_near + a*0.1 in both directions), with
// maintained ru = rcp(u) so thit = log2(u_far*ru)*raL — the ratio is formed
// linearly THEN logged (r15's lnext-lcur scheme had ulp(|l|)*1/a error
// amplification -> ld absmax 0.08; this restores r13 numerics).
// Two trans/iter: log2 (chain) + rcp (off-chain). raL from the LDS slot.
// Equilibrium inside cell: u_far <= 0 -> log2(neg) = NaN -> cross false
// (matches reference's ratio-clamp no-cross; verified by r15's passing z).
__device__ __forceinline__ void flow_fast(float x0, const f32x2* alcol,
                                          int c0, float aL0, float raL0, float v0,
                                          float& zo, float& ldo) {
  bool right = (v0 >= 0.0f);
  int dirI = right ? 1 : -1;
  float xc0 = (float)(right ? c0 + 1 : c0) * 0.1f;
  const float C01 = 0.1f * LN2F;

  float u = fabsf(v0);
  float ru = __builtin_amdgcn_rcpf(u);
  float ru0 = ru;
  float aL = aL0, raL = raL0;
  float t = 1.0f;
  int c = c0;
  bool cross;

  // prefetch next cell's slot
  int cn = c + dirI; cn = cn < 0 ? 0 : (cn > 9 ? 9 : cn);
  f32x2 sn = alcol[cn * THREADS];

  // peeled first step (entry at x0, not a boundary)
  {
    float dxL = fabsf(xc0 - x0) * LN2F;
    float uxc = fmaf(aL, dxL, u);
    float l2 = log2_hw(uxc * ru);         // NaN if equilibrium inside
    float thit = l2 * raL;
    cross = thit < t;                     // NaN -> false
    t = cross ? t - thit : t;
    float run = __builtin_amdgcn_rcpf(uxc);  // off-chain
    u = cross ? uxc : u;
    ru = cross ? run : ru;
    aL = cross ? sn[0] : aL;
    raL = cross ? sn[1] : raL;
    c = cross ? cn : c;
  }
  if (!__all(!cross)) {
    cn = c + dirI; cn = cn < 0 ? 0 : (cn > 9 ? 9 : cn);
    sn = alcol[cn * THREADS];
    for (int it = 1; it < NCELL; ++it) {
      float uxc = fmaf(aL, C01, u);       // u(far) = u(entry) + a*0.1 (log2-units)
      float l2 = log2_hw(uxc * ru);
      float thit = l2 * raL;
      cross = cross && (thit < t);        // sticky: frozen stays frozen
      t = cross ? t - thit : t;
      float run = __builtin_amdgcn_rcpf(uxc);
      u = cross ? uxc : u;
      ru = cross ? run : ru;
      aL = cross ? sn[0] : aL;
      raL = cross ? sn[1] : raL;
      c = cross ? cn : c;
      if (__all(!cross)) break;
      cn = c + dirI; cn = cn < 0 ? 0 : (cn > 9 ? 9 : cn);
      sn = alcol[cn * THREADS];           // prefetch for next iter
    }
  }
  // epilogue: reconstruct terminal cell, evolve once; ld via linear ratio
  // then log (never recompute v(z) — r12 lesson).
  float aF = aL * LN2F;
  bool moved = t != 1.0f;
  float ceF = (float)(right ? c : c + 1) * 0.1f;  // terminal entry boundary
  float x_e = moved ? ceF : x0;
  float sgn = right ? 1.0f : -1.0f;
  float ventry = u * sgn;
  float bF = fmaf(-aF, x_e, ventry);              // b = v(x_e) - a*x_e
  float bsa = bF * (raL * RLN2F);                 // b/a = b * (1/aF)
  float E = exp2_hw(aL * t);                      // exp(aF*t)
  float z = fmaf(x_e + bsa, E, -bsa);
  bool done = !cross;         // exhausted-while-crossing: stay at boundary
  z = done ? z : x_e;
  float ld = LN2F * log2_hw(u * ru0);             // telescoped to terminal entry
  ld += done ? aF * t : 0.0f;                     // evolve factor, log-space exact
  zo = z;
  ldo = ld;
}

// SLOW fallback (r11/r13 semantics incl. lin/tiny guards), rolled-v form:
// b is reconstructed from (a, phiC, ventry) where needed since vL is no
// longer in LDS. Wave-uniform entry, essentially never taken.
__device__ __noinline__ void flow_slow(float x0, const f32x2* alcol,
                                       int c0, float a0, float v0,
                                       float& zo, float& ldo) {
  bool right = (v0 >= 0.0f);
  float d01 = right ? 0.1f : -0.1f;
  int dirI = right ? 1 : -1;
  float a = a0;
  float xc = (float)(right ? (c0 + 1) : c0) * 0.1f;
  float rv0 = __builtin_amdgcn_rcpf(v0);
  float rv = rv0;
  bool tiny = fabsf(v0) < 1e-14f;
  bool lin = fabsf(a) < 1e-10f;
  float ra = __builtin_amdgcn_rcpf(lin ? 1.0f : a);
  float phiC = x0;
  float ventry = v0;
  float t = 1.0f;
  bool cross = false;
  int c = c0;

  int cn = c + dirI; cn = cn < 0 ? 0 : (cn > 9 ? 9 : cn);
  f32x2 sn = alcol[cn * THREADS];
  float an = sn[0] * LN2F;
  bool linn = fabsf(an) < 1e-10f;
  float ran = __builtin_amdgcn_rcpf(linn ? 1.0f : an);

  for (int it = 0; it < NCELL; ++it) {
    float vxc = fmaf(a, xc - phiC, ventry);   // v at far boundary (continuity)
    float ratio = fmaxf(vxc * rv, 1e-30f);
    float l = __logf(ratio);
    float thit = l * ra;
    if (lin) {
      float b = fmaf(-a, phiC, ventry);
      float sb = (fabsf(b) < 1e-30f) ? 1.0f : b;
      thit = (xc - phiC) * __builtin_amdgcn_rcpf(sb);
    }
    thit = tiny ? __builtin_inff() : thit;
    bool crN = (thit < t);
    cross = (it == 0) ? crN : (cross && crN);
    t = cross ? (t - thit) : t;
    phiC = cross ? xc : phiC;
    float rvn = __builtin_amdgcn_rcpf(vxc);
    rv = cross ? rvn : rv;
    ventry = cross ? vxc : ventry;
    tiny = cross ? (fabsf(vxc) < 1e-14f) : tiny;
    a = cross ? an : a;
    lin = cross ? linn : lin;
    ra = cross ? ran : ra;
    xc = cross ? (xc + d01) : xc;
    c = cross ? cn : c;
    if (__all(!cross)) break;
    cn = c + dirI; cn = cn < 0 ? 0 : (cn > 9 ? 9 : cn);
    sn = alcol[cn * THREADS];
    an = sn[0] * LN2F;
    linn = fabsf(an) < 1e-10f;
    ran = __builtin_amdgcn_rcpf(linn ? 1.0f : an);
  }
  bool done = !cross;
  float ld = __logf(fmaxf(ventry * rv0, 1e-30f));
  float b = fmaf(-a, phiC, ventry);
  bool linf = fabsf(a) < 1e-10f;
  float rsaf = __builtin_amdgcn_rcpf(linf ? 1.0f : a);
  float bsa = b * rsaf;
  float E = __expf(a * t);
  float pnl = fmaf(phiC + bsa, E, -bsa);
  float pli = fmaf(b, t, phiC);
  float p1 = linf ? pli : pnl;
  zo = done ? p1 : phiC;
  ldo = ld + (done ? a * t : 0.0f);
}

__device__ __forceinline__ void flow_dev(float x0, const f32x2* alcol,
                                         int c0, float aL0, float raL0, float v0,
                                         float aminL, float bmin,
                                         float& zo, float& ldo) {
  bool risky = (aminL < LIN_THR_L) || (bmin < 1e-12f) || (fabsf(v0) < 1e-12f);
  if (__any(risky)) {
    flow_slow(x0, alcol, c0, aL0 * LN2F, v0, zo, ldo);
  } else {
    flow_fast(x0, alcol, c0, aL0, raL0, v0, zo, ldo);
  }
}

__device__ __forceinline__ int cell_of(float x) {
  int c = (int)(x * 10.0f);
  return c < 0 ? 0 : (c > 9 ? 9 : c);
}

__global__ __launch_bounds__(THREADS, 4) void cpab2d_kernel(
    const float* __restrict__ x,
    const float* __restrict__ m1w2, const float* __restrict__ m1b2,
    const float* __restrict__ m2w2, const float* __restrict__ m2b2,
    const float* __restrict__ wsf,
    float* __restrict__ out, int n) {
  __shared__ f32x2 AL2[NCELL][THREADS];  // (aL, raL); [cell][tid]
  int i = blockIdx.x * THREADS + threadIdx.x;
  if (i >= n) return;

  float2 xi = reinterpret_cast<const float2*>(x)[i];
  // xs = x[:, [1,0]]: x1 = x[:,1], x2 = x[:,0]; both clipped first
  float x2v = fminf(fmaxf(xi.x, 1e-7f), 1.0f - 1e-7f);
  float x1v = fminf(fmaxf(xi.y, 1e-7f), 1.0f - 1e-7f);

  f32x2* alcol = &AL2[0][threadIdx.x];
  float aL0, raL0, v0, aminL, bmin;

  // theta2 = mlp(x1, m2); z2,g2 = flow(x2, theta2)
  int c0a = cell_of(x2v);
  mlp_A(x1v, m2w2, m2b2, wsf + 130, alcol, c0a, x2v, aL0, raL0, v0, aminL, bmin);
  float z2, ld2;
  flow_dev(x2v, alcol, c0a, aL0, raL0, v0, aminL, bmin, z2, ld2);

  // theta1 = mlp(z2, m1); z1,g1 = flow(x1, theta1)
  int c0b = cell_of(x1v);
  mlp_A(z2, m1w2, m1b2, wsf, alcol, c0b, x1v, aL0, raL0, v0, aminL, bmin);
  float z1, ld1;
  flow_dev(x1v, alcol, c0b, aL0, raL0, v0, aminL, bmin, z1, ld1);

  // z = [z2, z1]; log_dz_dx = [ld2, ld1]
  reinterpret_cast<float2*>(out)[i] = make_float2(z2, z1);
  reinterpret_cast<float2*>(out + 2 * (size_t)n)[i] = make_float2(ld2, ld1);
}

extern "C" void kernel_launch(void* const* d_in, const int* in_sizes, int n_in,
                              void* d_out, int out_size, void* d_ws, size_t ws_size,
                              hipStream_t stream) {
  const float* x    = (const float*)d_in[0];
  const float* m1w0 = (const float*)d_in[1];
  const float* m1b0 = (const float*)d_in[2];
  const float* m1w1 = (const float*)d_in[3];
  const float* m1b1 = (const float*)d_in[4];
  const float* m1w2 = (const float*)d_in[5];
  const float* m1b2 = (const float*)d_in[6];
  const float* m1w3 = (const float*)d_in[7];
  const float* m1b3 = (const float*)d_in[8];
  const float* m2w0 = (const float*)d_in[9];
  const float* m2b0 = (const float*)d_in[10];
  const float* m2w1 = (const float*)d_in[11];
  const float* m2b1 = (const float*)d_in[12];
  const float* m2w2 = (const float*)d_in[13];
  const float* m2b2 = (const float*)d_in[14];
  const float* m2w3 = (const float*)d_in[15];
  const float* m2b3 = (const float*)d_in[16];
  float* out = (float*)d_out;
  float* wsf = (float*)d_ws;
  int n = in_sizes[0] / 2;

  Basis bs;
  compute_basis_host(&bs);

  fold_kernel<<<1, THREADS, 0, stream>>>(
      m1w0, m1b0, m1w1, m1b1, m1w3, m1b3,
      m2w0, m2b0, m2w1, m2b1, m2w3, m2b3, wsf, bs);

  dim3 grid((n + THREADS - 1) / THREADS), block(THREADS);
  cpab2d_kernel<<<grid, block, 0, stream>>>(
      x, m1w2, m1b2, m2w2, m2b2, wsf, out, n);
}